// Round 10
// baseline (160.690 us; speedup 1.0000x reference)
//
#include <hip/hip_runtime.h>

// SparseLayer: out[n] = ((self[n] + sum_j neigh[n*32+j]) / 33) @ W + bias
// N=50000, NEIGH=32, D=128, fp32.
//
// R10 = R6 structure at NPW=3 with launch_bounds(256,7): VGPR budget ~73,
// natural footprint ~60 -> 7 waves/SIMD = 28 waves/CU (R6: 24). Single-
// variable occupancy probe; NT stream, h-split W sweep, shfl merges
// unchanged. Record: 16w->5.02 TB/s, 24w->5.44 TB/s, 32w->spills (VGPR
// capped at 32; do NOT use launch_bounds(.,8) with f32x4 code).

typedef float f32x4 __attribute__((ext_vector_type(4)));

constexpr int D       = 128;
constexpr int D4      = D / 4;            // 32
constexpr int NEIGH   = 32;
constexpr int WAVES   = 4;
constexpr int THREADS = WAVES * 64;       // 256
constexpr int NPW     = 3;                // nodes per wave
constexpr int NPB     = WAVES * NPW;      // 12 nodes per block -> 4167 blocks

__global__ __launch_bounds__(THREADS, 7)  // 7 waves/SIMD = 28 waves/CU
void sparse_layer_v7(const float* __restrict__ self_vecs,
                     const float* __restrict__ neigh_vecs,
                     const float* __restrict__ weight,
                     const float* __restrict__ bias,
                     float* __restrict__ out, int n_nodes)
{
    __shared__ float agg_lds[WAVES][NPW][D];   // 6 KiB

    const int wave = threadIdx.x >> 6;
    const int lane = threadIdx.x & 63;
    const int h    = lane >> 5;            // half: even/odd rows, low/high k
    const int c4   = lane & 31;            // float4 column

    const f32x4* s4 = reinterpret_cast<const f32x4*>(self_vecs);
    const f32x4* g4 = reinterpret_cast<const f32x4*>(neigh_vecs);
    const f32x4* w4 = reinterpret_cast<const f32x4*>(weight);
    constexpr float inv = 1.0f / (NEIGH + 1);

    const long base = (long)blockIdx.x * NPB + wave * NPW;

    // ---- phase 1: aggregate 3 nodes (16 linear 1-KB wave-loads each) ----
    #pragma unroll
    for (int i = 0; i < NPW; ++i) {
        const long n = base + i;
        if (n >= n_nodes) break;           // wave-uniform
        const f32x4* p = g4 + n * (long)NEIGH * D4;
        f32x4 acc = (f32x4)0.0f;
        if (h == 0) acc = __builtin_nontemporal_load(&s4[n * D4 + c4]);
        #pragma unroll 8
        for (int l = 0; l < 16; ++l)
            acc += __builtin_nontemporal_load(&p[l * 64 + lane]);  // row 2l+h
        f32x4 tot;
        tot.x = acc.x + __shfl_xor(acc.x, 32);
        tot.y = acc.y + __shfl_xor(acc.y, 32);
        tot.z = acc.z + __shfl_xor(acc.z, 32);
        tot.w = acc.w + __shfl_xor(acc.w, 32);
        if (h == 0)
            reinterpret_cast<f32x4*>(agg_lds[wave][i])[c4] = tot * inv;
    }

    // ---- phase 2: one W sweep (L1/L2) computes all 3 nodes ----
    f32x4 o0 = (f32x4)0.0f, o1 = (f32x4)0.0f, o2 = (f32x4)0.0f;
    const f32x4* a0 = reinterpret_cast<const f32x4*>(agg_lds[wave][0]);
    const f32x4* a1 = reinterpret_cast<const f32x4*>(agg_lds[wave][1]);
    const f32x4* a2 = reinterpret_cast<const f32x4*>(agg_lds[wave][2]);

    #pragma unroll 4
    for (int k4 = 0; k4 < D4 / 2; ++k4) {
        const int kk = h * (D4 / 2) + k4;         // h-split k range
        f32x4 w0 = w4[(4 * kk + 0) * D4 + c4];    // L1/L2-resident, coalesced
        f32x4 w1 = w4[(4 * kk + 1) * D4 + c4];
        f32x4 w2 = w4[(4 * kk + 2) * D4 + c4];
        f32x4 w3 = w4[(4 * kk + 3) * D4 + c4];
        f32x4 b0 = a0[kk];                        // LDS broadcast within half
        f32x4 b1 = a1[kk];
        f32x4 b2 = a2[kk];
        o0 += b0.x * w0;  o0 += b0.y * w1;  o0 += b0.z * w2;  o0 += b0.w * w3;
        o1 += b1.x * w0;  o1 += b1.y * w1;  o1 += b1.z * w2;  o1 += b1.w * w3;
        o2 += b2.x * w0;  o2 += b2.y * w1;  o2 += b2.z * w2;  o2 += b2.w * w3;
    }

    // ---- cross-half merge + write ----
    const f32x4 bv = reinterpret_cast<const f32x4*>(bias)[c4];
    f32x4* o4 = reinterpret_cast<f32x4*>(out);

    o0.x += __shfl_xor(o0.x, 32);
    o0.y += __shfl_xor(o0.y, 32);
    o0.z += __shfl_xor(o0.z, 32);
    o0.w += __shfl_xor(o0.w, 32);
    if (h == 0 && base < n_nodes)
        __builtin_nontemporal_store(o0 + bv, &o4[base * D4 + c4]);

    o1.x += __shfl_xor(o1.x, 32);
    o1.y += __shfl_xor(o1.y, 32);
    o1.z += __shfl_xor(o1.z, 32);
    o1.w += __shfl_xor(o1.w, 32);
    if (h == 0 && base + 1 < n_nodes)
        __builtin_nontemporal_store(o1 + bv, &o4[(base + 1) * D4 + c4]);

    o2.x += __shfl_xor(o2.x, 32);
    o2.y += __shfl_xor(o2.y, 32);
    o2.z += __shfl_xor(o2.z, 32);
    o2.w += __shfl_xor(o2.w, 32);
    if (h == 0 && base + 2 < n_nodes)
        __builtin_nontemporal_store(o2 + bv, &o4[(base + 2) * D4 + c4]);
}

extern "C" void kernel_launch(void* const* d_in, const int* in_sizes, int n_in,
                              void* d_out, int out_size, void* d_ws, size_t ws_size,
                              hipStream_t stream) {
    const float* self_vecs  = (const float*)d_in[0];
    const float* neigh_vecs = (const float*)d_in[1];
    // d_in[2] = neigh_num (==32, compile-time NEIGH)
    const float* weight     = (const float*)d_in[3];
    const float* bias       = (const float*)d_in[4];
    float*       out        = (float*)d_out;

    const int n_nodes = in_sizes[0] / D;                 // 50000
    const int blocks  = (n_nodes + NPB - 1) / NPB;       // 4167
    hipLaunchKernelGGL(sparse_layer_v7, dim3(blocks), dim3(THREADS), 0, stream,
                       self_vecs, neigh_vecs, weight, bias, out, n_nodes);
}